// Round 1
// baseline (782.350 us; speedup 1.0000x reference)
//
#include <hip/hip_runtime.h>
#include <stdint.h>

#define N_PTS 16384
#define TAU_C 0.001f
#define N_ITER 10
#define BJ 1024      // target points per j-chunk (LDS tile)
#define MI 2         // ref points per thread

struct State {
  float x[6];    // accepted params
  float xc[6];   // candidate params
  float dx[6];   // last step
  float Rc[9];   // candidate rotation (row-major)
  float tc[3];   // candidate translation
  float H[21];   // accepted J^T J, upper triangle
  float g[6];    // accepted J^T r
  float F, mu, nu;
};

// ---------------- se3 exp (matches reference formulas, fp32) ----------------
__device__ void se3_exp_rt(const float* x, float* R, float* t) {
  float wx = x[0], wy = x[1], wz = x[2];
  float vx = x[3], vy = x[4], vz = x[5];
  float th2 = wx*wx + wy*wy + wz*wz;
  float th = sqrtf(th2);
  float A, B, C;
  if (th < 1e-8f) {
    A = 1.0f - th2 / 6.0f;
    B = 0.5f - th2 / 24.0f;
    C = 1.0f / 6.0f - th2 / 120.0f;
  } else {
    float s = sinf(th), c = cosf(th);
    A = s / th;
    B = (1.0f - c) / th2;
    C = (th - s) / (th2 * th);
  }
  float W[9]  = {0.f, -wz, wy,  wz, 0.f, -wx,  -wy, wx, 0.f};
  float W2[9];
  #pragma unroll
  for (int r = 0; r < 3; r++)
    #pragma unroll
    for (int c = 0; c < 3; c++)
      W2[3*r+c] = W[3*r+0]*W[0+c] + W[3*r+1]*W[3+c] + W[3*r+2]*W[6+c];
  float V[9];
  #pragma unroll
  for (int k = 0; k < 9; k++) {
    float I = (k == 0 || k == 4 || k == 8) ? 1.f : 0.f;
    R[k] = I + A * W[k] + B * W2[k];
    V[k] = I + B * W[k] + C * W2[k];
  }
  t[0] = V[0]*vx + V[1]*vy + V[2]*vz;
  t[1] = V[3]*vx + V[4]*vy + V[5]*vz;
  t[2] = V[6]*vx + V[7]*vy + V[8]*vz;
}

// ---------------- prep: pack targets, init keys + state ----------------
__global__ void prep_kernel(const float* __restrict__ trg,
                            float4* __restrict__ packed,
                            unsigned long long* __restrict__ keys,
                            State* st) {
  int i = blockIdx.x * blockDim.x + threadIdx.x;
  if (i < N_PTS) {
    float tx = trg[3*i], ty = trg[3*i+1], tz = trg[3*i+2];
    packed[i] = make_float4(-2.f*tx, -2.f*ty, -2.f*tz, tx*tx + ty*ty + tz*tz);
    keys[i] = 0xFFFFFFFFFFFFFFFFULL;
  }
  if (blockIdx.x == 0 && threadIdx.x == 0) {
    #pragma unroll
    for (int k = 0; k < 6; k++) { st->x[k] = 0.f; st->xc[k] = 0.f; st->dx[k] = 0.f; }
    #pragma unroll
    for (int k = 0; k < 9; k++) st->Rc[k] = (k % 4 == 0) ? 1.f : 0.f;
    st->tc[0] = st->tc[1] = st->tc[2] = 0.f;
    st->nu = 2.f;
  }
}

// ---------------- NN: brute-force argmin over a j-chunk ----------------
__global__ __launch_bounds__(256) void nn_kernel(const float* __restrict__ ref,
                                                 const float4* __restrict__ packed,
                                                 const State* __restrict__ st,
                                                 unsigned long long* __restrict__ keys) {
  __shared__ float4 tile[BJ];
  const int tid = threadIdx.x;
  const int jbase = blockIdx.y * BJ;
  #pragma unroll
  for (int k = 0; k < BJ/256; k++)
    tile[tid + 256*k] = packed[jbase + tid + 256*k];

  // candidate transform (uniform)
  const float R00 = st->Rc[0], R01 = st->Rc[1], R02 = st->Rc[2];
  const float R10 = st->Rc[3], R11 = st->Rc[4], R12 = st->Rc[5];
  const float R20 = st->Rc[6], R21 = st->Rc[7], R22 = st->Rc[8];
  const float t0 = st->tc[0], t1 = st->tc[1], t2 = st->tc[2];

  const int i0 = blockIdx.x * (256 * MI) + tid;
  float px[MI], py[MI], pz[MI];
  #pragma unroll
  for (int m = 0; m < MI; m++) {
    int i = i0 + 256*m;
    float ax = ref[3*i] - t0, ay = ref[3*i+1] - t1, az = ref[3*i+2] - t2;
    // ref_t = R^T (p - t)
    px[m] = R00*ax + R10*ay + R20*az;
    py[m] = R01*ax + R11*ay + R21*az;
    pz[m] = R02*ax + R12*ay + R22*az;
  }
  __syncthreads();

  float best[MI];
  int bj[MI];
  #pragma unroll
  for (int m = 0; m < MI; m++) { best[m] = 3.4e38f; bj[m] = 0; }

  #pragma unroll 8
  for (int jj = 0; jj < BJ; jj++) {
    float4 tq = tile[jj];
    #pragma unroll
    for (int m = 0; m < MI; m++) {
      // score = |t|^2 - 2 p.t  (constant |p|^2 per row omitted; argmin unchanged)
      float s = fmaf(px[m], tq.x, tq.w);
      s = fmaf(py[m], tq.y, s);
      s = fmaf(pz[m], tq.z, s);
      if (s < best[m]) { best[m] = s; bj[m] = jj; }
    }
  }

  #pragma unroll
  for (int m = 0; m < MI; m++) {
    int i = i0 + 256*m;
    unsigned ub = __float_as_uint(best[m]);
    ub = (ub & 0x80000000u) ? ~ub : (ub | 0x80000000u);   // monotone float->uint
    unsigned long long key = ((unsigned long long)ub << 32) |
                             (unsigned long long)(unsigned)(jbase + bj[m]);
    atomicMin(&keys[i], key);
  }
}

// ---------------- accumulate H,g,F + LM scalar update (1 block) ----------------
__global__ __launch_bounds__(256) void accum_lm_kernel(const float* __restrict__ ref,
                                                       const float* __restrict__ trg,
                                                       const float* __restrict__ nrm,
                                                       unsigned long long* __restrict__ keys,
                                                       State* st, float* out, int mode) {
  const int tid = threadIdx.x;
  float acc[28];
  #pragma unroll
  for (int k = 0; k < 28; k++) acc[k] = 0.f;

  const float R00 = st->Rc[0], R01 = st->Rc[1], R02 = st->Rc[2];
  const float R10 = st->Rc[3], R11 = st->Rc[4], R12 = st->Rc[5];
  const float R20 = st->Rc[6], R21 = st->Rc[7], R22 = st->Rc[8];
  const float t0 = st->tc[0], t1 = st->tc[1], t2 = st->tc[2];

  #pragma unroll 4
  for (int k = 0; k < N_PTS / 256; k++) {
    int i = tid + 256*k;
    unsigned long long key = keys[i];
    keys[i] = 0xFFFFFFFFFFFFFFFFULL;   // reset for next eval
    int j = (int)(unsigned)(key & 0xFFFFFFFFULL);

    float nx0 = nrm[3*j], ny0 = nrm[3*j+1], nz0 = nrm[3*j+2];
    float qx = trg[3*j], qy = trg[3*j+1], qz = trg[3*j+2];
    // n = R * normal ; p = R * trg + t
    float nx = R00*nx0 + R01*ny0 + R02*nz0;
    float ny = R10*nx0 + R11*ny0 + R12*nz0;
    float nz = R20*nx0 + R21*ny0 + R22*nz0;
    float pxx = R00*qx + R01*qy + R02*qz + t0;
    float pyy = R10*qx + R11*qy + R12*qz + t1;
    float pzz = R20*qx + R21*qy + R22*qz + t2;

    float rx = ref[3*i], ry = ref[3*i+1], rz = ref[3*i+2];
    float dxx = rx - pxx, dyy = ry - pyy, dzz = rz - pzz;
    float r = nx*dxx + ny*dyy + nz*dzz;

    float J[6];
    J[0] = ry*nz - rz*ny;
    J[1] = rz*nx - rx*nz;
    J[2] = rx*ny - ry*nx;
    J[3] = nx; J[4] = ny; J[5] = nz;

    int c21 = 0;
    #pragma unroll
    for (int a = 0; a < 6; a++)
      #pragma unroll
      for (int b = a; b < 6; b++)
        acc[c21++] = fmaf(J[a], J[b], acc[c21]);
    #pragma unroll
    for (int a = 0; a < 6; a++) acc[21+a] = fmaf(J[a], r, acc[21+a]);
    acc[27] = fmaf(r, r, acc[27]);
  }

  // block reduction: wave shuffle then cross-wave via LDS
  #pragma unroll
  for (int kk = 0; kk < 28; kk++) {
    float v = acc[kk];
    for (int off = 32; off; off >>= 1) v += __shfl_down(v, off);
    acc[kk] = v;
  }
  __shared__ float red[4][28];
  int wave = tid >> 6, lane = tid & 63;
  if (lane == 0) {
    #pragma unroll
    for (int kk = 0; kk < 28; kk++) red[wave][kk] = acc[kk];
  }
  __syncthreads();

  if (tid == 0) {
    float tot[28];
    #pragma unroll
    for (int kk = 0; kk < 28; kk++)
      tot[kk] = red[0][kk] + red[1][kk] + red[2][kk] + red[3][kk];

    float Fn = tot[27];
    float mu, nu;

    if (mode == 0) {
      #pragma unroll
      for (int k = 0; k < 6; k++) st->x[k] = st->xc[k];
      #pragma unroll
      for (int k = 0; k < 21; k++) st->H[k] = tot[k];
      #pragma unroll
      for (int k = 0; k < 6; k++) st->g[k] = tot[21+k];
      st->F = Fn;
      float md = tot[0];
      md = fmaxf(md, tot[6]); md = fmaxf(md, tot[11]); md = fmaxf(md, tot[15]);
      md = fmaxf(md, tot[18]); md = fmaxf(md, tot[20]);
      mu = TAU_C * md;
      nu = 2.f;
    } else {
      mu = st->mu; nu = st->nu;
      float denom = 0.f;
      #pragma unroll
      for (int k = 0; k < 6; k++) denom += st->dx[k] * (mu * st->dx[k] - st->g[k]);
      if (fabsf(denom) < 1e-12f) denom = 1e-12f;
      float rho = (st->F - Fn) / denom;
      if (rho > 0.f) {
        #pragma unroll
        for (int k = 0; k < 6; k++) st->x[k] = st->xc[k];
        #pragma unroll
        for (int k = 0; k < 21; k++) st->H[k] = tot[k];
        #pragma unroll
        for (int k = 0; k < 6; k++) st->g[k] = tot[21+k];
        st->F = Fn;
        float tcube = 2.f * rho - 1.f;
        mu = mu * fmaxf(1.f / 3.f, 1.f - tcube * tcube * tcube);
        nu = 2.f;
      } else {
        mu = mu * nu;
        nu = 2.f * nu;
      }
    }
    st->mu = mu; st->nu = nu;

    if (mode < N_ITER) {
      // solve (H + mu I) d = -g ; SPD -> unpivoted Gauss, fully unrolled (registers)
      float A[6][7];
      int c21 = 0;
      #pragma unroll
      for (int a = 0; a < 6; a++)
        #pragma unroll
        for (int b = a; b < 6; b++) { A[a][b] = st->H[c21]; A[b][a] = st->H[c21]; c21++; }
      #pragma unroll
      for (int a = 0; a < 6; a++) { A[a][a] += mu; A[a][6] = -st->g[a]; }
      #pragma unroll
      for (int col = 0; col < 6; col++) {
        float inv = 1.f / A[col][col];
        #pragma unroll
        for (int rI = 0; rI < 6; rI++) {
          if (rI > col) {
            float f = A[rI][col] * inv;
            #pragma unroll
            for (int cc = 0; cc < 7; cc++)
              if (cc >= col) A[rI][cc] -= f * A[col][cc];
          }
        }
      }
      float d[6];
      #pragma unroll
      for (int rI = 5; rI >= 0; rI--) {
        float s = A[rI][6];
        #pragma unroll
        for (int cc = 0; cc < 6; cc++)
          if (cc > rI) s -= A[rI][cc] * d[cc];
        d[rI] = s / A[rI][rI];
      }
      float Rn[9], tn[3];
      #pragma unroll
      for (int k = 0; k < 6; k++) { st->dx[k] = d[k]; st->xc[k] = st->x[k] + d[k]; }
      se3_exp_rt(st->xc, Rn, tn);
      #pragma unroll
      for (int k = 0; k < 9; k++) st->Rc[k] = Rn[k];
      #pragma unroll
      for (int k = 0; k < 3; k++) st->tc[k] = tn[k];
    } else {
      float Rn[9], tn[3];
      se3_exp_rt(st->x, Rn, tn);
      out[0] = Rn[0]; out[1] = Rn[1]; out[2]  = Rn[2]; out[3]  = tn[0];
      out[4] = Rn[3]; out[5] = Rn[4]; out[6]  = Rn[5]; out[7]  = tn[1];
      out[8] = Rn[6]; out[9] = Rn[7]; out[10] = Rn[8]; out[11] = tn[2];
      out[12] = 0.f; out[13] = 0.f; out[14] = 0.f; out[15] = 1.f;
      out[16] = st->F / (float)N_PTS;
    }
  }
}

extern "C" void kernel_launch(void* const* d_in, const int* in_sizes, int n_in,
                              void* d_out, int out_size, void* d_ws, size_t ws_size,
                              hipStream_t stream) {
  const float* ref = (const float*)d_in[0];
  const float* trg = (const float*)d_in[1];
  const float* nrm = (const float*)d_in[2];
  float* out = (float*)d_out;

  char* ws = (char*)d_ws;
  float4* packed = (float4*)ws;                                        // 256 KB
  unsigned long long* keys = (unsigned long long*)(ws + 262144);       // 128 KB
  State* st = (State*)(ws + 262144 + 131072);

  prep_kernel<<<64, 256, 0, stream>>>(trg, packed, keys, st);
  for (int e = 0; e <= N_ITER; e++) {
    nn_kernel<<<dim3(N_PTS / (256 * MI), N_PTS / BJ), 256, 0, stream>>>(ref, packed, st, keys);
    accum_lm_kernel<<<1, 256, 0, stream>>>(ref, trg, nrm, keys, st, out, e);
  }
}

// Round 2
// 371.285 us; speedup vs baseline: 2.1071x; 2.1071x over previous
//
#include <hip/hip_runtime.h>
#include <stdint.h>

#define N_PTS 16384
#define TAU_C 0.001f
#define N_ITER 10
#define BJ 512       // target points per j-chunk (LDS tile)
#define MI 4         // ref points per thread
#define NGROUP (BJ / 8)

struct State {
  float x[6];    // accepted params
  float xc[6];   // candidate params
  float dx[6];   // last step
  float Rc[9];   // candidate rotation (row-major)
  float tc[3];   // candidate translation
  float H[21];   // accepted J^T J, upper triangle
  float g[6];    // accepted J^T r
  float F, mu, nu;
};

// ---------------- se3 exp (matches reference formulas, fp32) ----------------
__device__ void se3_exp_rt(const float* x, float* R, float* t) {
  float wx = x[0], wy = x[1], wz = x[2];
  float vx = x[3], vy = x[4], vz = x[5];
  float th2 = wx*wx + wy*wy + wz*wz;
  float th = sqrtf(th2);
  float A, B, C;
  if (th < 1e-8f) {
    A = 1.0f - th2 / 6.0f;
    B = 0.5f - th2 / 24.0f;
    C = 1.0f / 6.0f - th2 / 120.0f;
  } else {
    float s = sinf(th), c = cosf(th);
    A = s / th;
    B = (1.0f - c) / th2;
    C = (th - s) / (th2 * th);
  }
  float W[9]  = {0.f, -wz, wy,  wz, 0.f, -wx,  -wy, wx, 0.f};
  float W2[9];
  #pragma unroll
  for (int r = 0; r < 3; r++)
    #pragma unroll
    for (int c = 0; c < 3; c++)
      W2[3*r+c] = W[3*r+0]*W[0+c] + W[3*r+1]*W[3+c] + W[3*r+2]*W[6+c];
  float V[9];
  #pragma unroll
  for (int k = 0; k < 9; k++) {
    float I = (k == 0 || k == 4 || k == 8) ? 1.f : 0.f;
    R[k] = I + A * W[k] + B * W2[k];
    V[k] = I + B * W[k] + C * W2[k];
  }
  t[0] = V[0]*vx + V[1]*vy + V[2]*vz;
  t[1] = V[3]*vx + V[4]*vy + V[5]*vz;
  t[2] = V[6]*vx + V[7]*vy + V[8]*vz;
}

// ---------------- prep: pack targets, init keys + state ----------------
__global__ void prep_kernel(const float* __restrict__ trg,
                            float4* __restrict__ packed,
                            unsigned long long* __restrict__ keys,
                            State* st) {
  int i = blockIdx.x * blockDim.x + threadIdx.x;
  if (i < N_PTS) {
    float tx = trg[3*i], ty = trg[3*i+1], tz = trg[3*i+2];
    packed[i] = make_float4(-2.f*tx, -2.f*ty, -2.f*tz, tx*tx + ty*ty + tz*tz);
    keys[i] = 0xFFFFFFFFFFFFFFFFULL;
  }
  if (blockIdx.x == 0 && threadIdx.x == 0) {
    #pragma unroll
    for (int k = 0; k < 6; k++) { st->x[k] = 0.f; st->xc[k] = 0.f; st->dx[k] = 0.f; }
    #pragma unroll
    for (int k = 0; k < 9; k++) st->Rc[k] = (k % 4 == 0) ? 1.f : 0.f;
    st->tc[0] = st->tc[1] = st->tc[2] = 0.f;
    st->nu = 2.f;
  }
}

// ---------------- NN: brute-force argmin over a j-chunk ----------------
// Group-of-8 min-tree: per pair ~4.3 VALU ops; exact index recovered by
// rescanning the winning 8-group (bit-identical recompute). Strict `<`
// across groups + smallest-k-first within group == jnp.argmin tie-break.
__global__ __launch_bounds__(256) void nn_kernel(const float* __restrict__ ref,
                                                 const float4* __restrict__ packed,
                                                 const State* __restrict__ st,
                                                 unsigned long long* __restrict__ keys) {
  __shared__ float4 tile[BJ];
  const int tid = threadIdx.x;
  const int jbase = blockIdx.y * BJ;
  #pragma unroll
  for (int k = 0; k < BJ/256; k++)
    tile[tid + 256*k] = packed[jbase + tid + 256*k];

  // candidate transform (uniform, scalar)
  const float R00 = st->Rc[0], R01 = st->Rc[1], R02 = st->Rc[2];
  const float R10 = st->Rc[3], R11 = st->Rc[4], R12 = st->Rc[5];
  const float R20 = st->Rc[6], R21 = st->Rc[7], R22 = st->Rc[8];
  const float t0 = st->tc[0], t1 = st->tc[1], t2 = st->tc[2];

  const int i0 = blockIdx.x * (256 * MI) + tid;
  float px[MI], py[MI], pz[MI];
  #pragma unroll
  for (int m = 0; m < MI; m++) {
    int i = i0 + 256*m;
    float ax = ref[3*i] - t0, ay = ref[3*i+1] - t1, az = ref[3*i+2] - t2;
    // ref_t = R^T (p - t)
    px[m] = R00*ax + R10*ay + R20*az;
    py[m] = R01*ax + R11*ay + R21*az;
    pz[m] = R02*ax + R12*ay + R22*az;
  }
  __syncthreads();

  float best[MI];
  int bg[MI];
  #pragma unroll
  for (int m = 0; m < MI; m++) { best[m] = 3.4e38f; bg[m] = 0; }

  #pragma unroll 2
  for (int g = 0; g < NGROUP; g++) {
    float4 tq[8];
    #pragma unroll
    for (int k = 0; k < 8; k++) tq[k] = tile[8*g + k];
    #pragma unroll
    for (int m = 0; m < MI; m++) {
      float s[8];
      #pragma unroll
      for (int k = 0; k < 8; k++) {
        // score = |t|^2 - 2 p.t  (row-constant |p|^2 omitted; argmin unchanged)
        float v = fmaf(px[m], tq[k].x, tq[k].w);
        v = fmaf(py[m], tq[k].y, v);
        s[k] = fmaf(pz[m], tq[k].z, v);
      }
      float a = fminf(fminf(s[0], s[1]), s[2]);
      float b = fminf(fminf(s[3], s[4]), s[5]);
      float c = fminf(fminf(s[6], s[7]), a);
      float gm = fminf(b, c);
      if (gm < best[m]) { best[m] = gm; bg[m] = g; }
    }
  }

  // rescan winning group for the exact smallest index, then merge globally
  #pragma unroll
  for (int m = 0; m < MI; m++) {
    int jb = 8 * bg[m];
    int bj = 0;
    #pragma unroll
    for (int k = 7; k >= 0; k--) {
      float4 tq = tile[jb + k];
      float v = fmaf(px[m], tq.x, tq.w);
      v = fmaf(py[m], tq.y, v);
      v = fmaf(pz[m], tq.z, v);
      if (v == best[m]) bj = k;     // descending loop -> smallest k wins
    }
    int i = i0 + 256*m;
    unsigned ub = __float_as_uint(best[m]);
    ub = (ub & 0x80000000u) ? ~ub : (ub | 0x80000000u);   // monotone float->uint
    unsigned long long key = ((unsigned long long)ub << 32) |
                             (unsigned long long)(unsigned)(jbase + jb + bj);
    atomicMin(&keys[i], key);
  }
}

// ---------------- accum part: 64 blocks, each reduces 256 points ----------------
__global__ __launch_bounds__(256) void accum_part_kernel(const float* __restrict__ ref,
                                                         const float* __restrict__ trg,
                                                         const float* __restrict__ nrm,
                                                         unsigned long long* __restrict__ keys,
                                                         const State* __restrict__ st,
                                                         float* __restrict__ partials) {
  const int tid = threadIdx.x;
  const int i = blockIdx.x * 256 + tid;

  const float R00 = st->Rc[0], R01 = st->Rc[1], R02 = st->Rc[2];
  const float R10 = st->Rc[3], R11 = st->Rc[4], R12 = st->Rc[5];
  const float R20 = st->Rc[6], R21 = st->Rc[7], R22 = st->Rc[8];
  const float t0 = st->tc[0], t1 = st->tc[1], t2 = st->tc[2];

  unsigned long long key = keys[i];
  keys[i] = 0xFFFFFFFFFFFFFFFFULL;   // reset for next eval
  int j = (int)(unsigned)(key & 0xFFFFFFFFULL);

  float nx0 = nrm[3*j], ny0 = nrm[3*j+1], nz0 = nrm[3*j+2];
  float qx = trg[3*j], qy = trg[3*j+1], qz = trg[3*j+2];
  // n = R * normal ; p = R * trg + t
  float nx = R00*nx0 + R01*ny0 + R02*nz0;
  float ny = R10*nx0 + R11*ny0 + R12*nz0;
  float nz = R20*nx0 + R21*ny0 + R22*nz0;
  float pxx = R00*qx + R01*qy + R02*qz + t0;
  float pyy = R10*qx + R11*qy + R12*qz + t1;
  float pzz = R20*qx + R21*qy + R22*qz + t2;

  float rx = ref[3*i], ry = ref[3*i+1], rz = ref[3*i+2];
  float dxx = rx - pxx, dyy = ry - pyy, dzz = rz - pzz;
  float r = nx*dxx + ny*dyy + nz*dzz;

  float J[6];
  J[0] = ry*nz - rz*ny;
  J[1] = rz*nx - rx*nz;
  J[2] = rx*ny - ry*nx;
  J[3] = nx; J[4] = ny; J[5] = nz;

  float acc[28];
  int c21 = 0;
  #pragma unroll
  for (int a = 0; a < 6; a++)
    #pragma unroll
    for (int b = a; b < 6; b++)
      acc[c21++] = J[a] * J[b];
  #pragma unroll
  for (int a = 0; a < 6; a++) acc[21+a] = J[a] * r;
  acc[27] = r * r;

  // wave shuffle reduce, then cross-wave via LDS
  #pragma unroll
  for (int kk = 0; kk < 28; kk++) {
    float v = acc[kk];
    for (int off = 32; off; off >>= 1) v += __shfl_down(v, off);
    acc[kk] = v;
  }
  __shared__ float red[4][28];
  int wave = tid >> 6, lane = tid & 63;
  if (lane == 0) {
    #pragma unroll
    for (int kk = 0; kk < 28; kk++) red[wave][kk] = acc[kk];
  }
  __syncthreads();
  if (tid < 28) {
    // partials layout: [component][block] so lm_kernel reads contiguously
    partials[tid * 64 + blockIdx.x] =
        red[0][tid] + red[1][tid] + red[2][tid] + red[3][tid];
  }
}

// ---------------- LM scalar update (1 block, 64 threads) ----------------
__global__ __launch_bounds__(64) void lm_kernel(const float* __restrict__ partials,
                                                State* st, float* out, int mode) {
  __shared__ float tot[28];
  const int tid = threadIdx.x;
  if (tid < 28) {
    float s = 0.f;
    #pragma unroll
    for (int b = 0; b < 64; b++) s += partials[tid * 64 + b];
    tot[tid] = s;
  }
  __syncthreads();

  if (tid == 0) {
    float Fn = tot[27];
    float mu, nu;

    if (mode == 0) {
      #pragma unroll
      for (int k = 0; k < 6; k++) st->x[k] = st->xc[k];
      #pragma unroll
      for (int k = 0; k < 21; k++) st->H[k] = tot[k];
      #pragma unroll
      for (int k = 0; k < 6; k++) st->g[k] = tot[21+k];
      st->F = Fn;
      float md = tot[0];
      md = fmaxf(md, tot[6]); md = fmaxf(md, tot[11]); md = fmaxf(md, tot[15]);
      md = fmaxf(md, tot[18]); md = fmaxf(md, tot[20]);
      mu = TAU_C * md;
      nu = 2.f;
    } else {
      mu = st->mu; nu = st->nu;
      float denom = 0.f;
      #pragma unroll
      for (int k = 0; k < 6; k++) denom += st->dx[k] * (mu * st->dx[k] - st->g[k]);
      if (fabsf(denom) < 1e-12f) denom = 1e-12f;
      float rho = (st->F - Fn) / denom;
      if (rho > 0.f) {
        #pragma unroll
        for (int k = 0; k < 6; k++) st->x[k] = st->xc[k];
        #pragma unroll
        for (int k = 0; k < 21; k++) st->H[k] = tot[k];
        #pragma unroll
        for (int k = 0; k < 6; k++) st->g[k] = tot[21+k];
        st->F = Fn;
        float tcube = 2.f * rho - 1.f;
        mu = mu * fmaxf(1.f / 3.f, 1.f - tcube * tcube * tcube);
        nu = 2.f;
      } else {
        mu = mu * nu;
        nu = 2.f * nu;
      }
    }
    st->mu = mu; st->nu = nu;

    if (mode < N_ITER) {
      // solve (H + mu I) d = -g ; SPD -> unpivoted Gauss, fully unrolled
      float A[6][7];
      int c21 = 0;
      #pragma unroll
      for (int a = 0; a < 6; a++)
        #pragma unroll
        for (int b = a; b < 6; b++) { A[a][b] = st->H[c21]; A[b][a] = st->H[c21]; c21++; }
      #pragma unroll
      for (int a = 0; a < 6; a++) { A[a][a] += mu; A[a][6] = -st->g[a]; }
      #pragma unroll
      for (int col = 0; col < 6; col++) {
        float inv = 1.f / A[col][col];
        #pragma unroll
        for (int rI = 0; rI < 6; rI++) {
          if (rI > col) {
            float f = A[rI][col] * inv;
            #pragma unroll
            for (int cc = 0; cc < 7; cc++)
              if (cc >= col) A[rI][cc] -= f * A[col][cc];
          }
        }
      }
      float d[6];
      #pragma unroll
      for (int rI = 5; rI >= 0; rI--) {
        float s = A[rI][6];
        #pragma unroll
        for (int cc = 0; cc < 6; cc++)
          if (cc > rI) s -= A[rI][cc] * d[cc];
        d[rI] = s / A[rI][rI];
      }
      float Rn[9], tn[3];
      #pragma unroll
      for (int k = 0; k < 6; k++) { st->dx[k] = d[k]; st->xc[k] = st->x[k] + d[k]; }
      se3_exp_rt(st->xc, Rn, tn);
      #pragma unroll
      for (int k = 0; k < 9; k++) st->Rc[k] = Rn[k];
      #pragma unroll
      for (int k = 0; k < 3; k++) st->tc[k] = tn[k];
    } else {
      float Rn[9], tn[3];
      se3_exp_rt(st->x, Rn, tn);
      out[0] = Rn[0]; out[1] = Rn[1]; out[2]  = Rn[2]; out[3]  = tn[0];
      out[4] = Rn[3]; out[5] = Rn[4]; out[6]  = Rn[5]; out[7]  = tn[1];
      out[8] = Rn[6]; out[9] = Rn[7]; out[10] = Rn[8]; out[11] = tn[2];
      out[12] = 0.f; out[13] = 0.f; out[14] = 0.f; out[15] = 1.f;
      out[16] = st->F / (float)N_PTS;
    }
  }
}

extern "C" void kernel_launch(void* const* d_in, const int* in_sizes, int n_in,
                              void* d_out, int out_size, void* d_ws, size_t ws_size,
                              hipStream_t stream) {
  const float* ref = (const float*)d_in[0];
  const float* trg = (const float*)d_in[1];
  const float* nrm = (const float*)d_in[2];
  float* out = (float*)d_out;

  char* ws = (char*)d_ws;
  float4* packed = (float4*)ws;                                        // 256 KB
  unsigned long long* keys = (unsigned long long*)(ws + 262144);       // 128 KB
  float* partials = (float*)(ws + 262144 + 131072);                    // 7 KB
  State* st = (State*)(ws + 262144 + 131072 + 8192);

  prep_kernel<<<64, 256, 0, stream>>>(trg, packed, keys, st);
  for (int e = 0; e <= N_ITER; e++) {
    nn_kernel<<<dim3(N_PTS / (256 * MI), N_PTS / BJ), 256, 0, stream>>>(ref, packed, st, keys);
    accum_part_kernel<<<64, 256, 0, stream>>>(ref, trg, nrm, keys, st, partials);
    lm_kernel<<<1, 64, 0, stream>>>(partials, st, out, e);
  }
}

// Round 3
// 370.419 us; speedup vs baseline: 2.1121x; 1.0023x over previous
//
#include <hip/hip_runtime.h>
#include <stdint.h>

#define N_PTS 16384
#define TAU_C 0.001f
#define N_ITER 10
#define BJ 512       // target points per j-chunk (LDS tile)
#define MI 4         // ref points per thread
#define NGROUP (BJ / 8)

struct State {
  float x[6];    // accepted params
  float xc[6];   // candidate params
  float dx[6];   // last step
  float Rc[9];   // candidate rotation (row-major)
  float tc[3];   // candidate translation
  float H[21];   // accepted J^T J, upper triangle
  float g[6];    // accepted J^T r
  float F, mu, nu;
};

// ---------------- se3 exp (matches reference formulas, fp32) ----------------
__device__ void se3_exp_rt(const float* x, float* R, float* t) {
  float wx = x[0], wy = x[1], wz = x[2];
  float vx = x[3], vy = x[4], vz = x[5];
  float th2 = wx*wx + wy*wy + wz*wz;
  float th = sqrtf(th2);
  float A, B, C;
  if (th < 1e-8f) {
    A = 1.0f - th2 / 6.0f;
    B = 0.5f - th2 / 24.0f;
    C = 1.0f / 6.0f - th2 / 120.0f;
  } else {
    float s = sinf(th), c = cosf(th);
    A = s / th;
    B = (1.0f - c) / th2;
    C = (th - s) / (th2 * th);
  }
  float W[9]  = {0.f, -wz, wy,  wz, 0.f, -wx,  -wy, wx, 0.f};
  float W2[9];
  #pragma unroll
  for (int r = 0; r < 3; r++)
    #pragma unroll
    for (int c = 0; c < 3; c++)
      W2[3*r+c] = W[3*r+0]*W[0+c] + W[3*r+1]*W[3+c] + W[3*r+2]*W[6+c];
  float V[9];
  #pragma unroll
  for (int k = 0; k < 9; k++) {
    float I = (k == 0 || k == 4 || k == 8) ? 1.f : 0.f;
    R[k] = I + A * W[k] + B * W2[k];
    V[k] = I + B * W[k] + C * W2[k];
  }
  t[0] = V[0]*vx + V[1]*vy + V[2]*vz;
  t[1] = V[3]*vx + V[4]*vy + V[5]*vz;
  t[2] = V[6]*vx + V[7]*vy + V[8]*vz;
}

// ---------------- prep: pack targets, init keys + state ----------------
__global__ void prep_kernel(const float* __restrict__ trg,
                            float4* __restrict__ packed,
                            unsigned long long* __restrict__ keys,
                            State* st) {
  int i = blockIdx.x * blockDim.x + threadIdx.x;
  if (i < N_PTS) {
    float tx = trg[3*i], ty = trg[3*i+1], tz = trg[3*i+2];
    packed[i] = make_float4(-2.f*tx, -2.f*ty, -2.f*tz, tx*tx + ty*ty + tz*tz);
    keys[i] = 0xFFFFFFFFFFFFFFFFULL;
  }
  if (blockIdx.x == 0 && threadIdx.x == 0) {
    #pragma unroll
    for (int k = 0; k < 6; k++) { st->x[k] = 0.f; st->xc[k] = 0.f; st->dx[k] = 0.f; }
    #pragma unroll
    for (int k = 0; k < 9; k++) st->Rc[k] = (k % 4 == 0) ? 1.f : 0.f;
    st->tc[0] = st->tc[1] = st->tc[2] = 0.f;
    st->nu = 2.f;
  }
}

// ---------------- NN: brute-force argmin over a j-chunk ----------------
// Group-of-8 min-tree: per pair ~4.3 VALU ops; exact index recovered by
// rescanning the winning 8-group (bit-identical recompute). Strict `<`
// across groups + smallest-k-first within group == jnp.argmin tie-break.
__global__ __launch_bounds__(256) void nn_kernel(const float* __restrict__ ref,
                                                 const float4* __restrict__ packed,
                                                 const State* __restrict__ st,
                                                 unsigned long long* __restrict__ keys) {
  __shared__ float4 tile[BJ];
  const int tid = threadIdx.x;
  const int jbase = blockIdx.y * BJ;
  #pragma unroll
  for (int k = 0; k < BJ/256; k++)
    tile[tid + 256*k] = packed[jbase + tid + 256*k];

  // candidate transform (uniform, scalar)
  const float R00 = st->Rc[0], R01 = st->Rc[1], R02 = st->Rc[2];
  const float R10 = st->Rc[3], R11 = st->Rc[4], R12 = st->Rc[5];
  const float R20 = st->Rc[6], R21 = st->Rc[7], R22 = st->Rc[8];
  const float t0 = st->tc[0], t1 = st->tc[1], t2 = st->tc[2];

  const int i0 = blockIdx.x * (256 * MI) + tid;
  float px[MI], py[MI], pz[MI];
  #pragma unroll
  for (int m = 0; m < MI; m++) {
    int i = i0 + 256*m;
    float ax = ref[3*i] - t0, ay = ref[3*i+1] - t1, az = ref[3*i+2] - t2;
    // ref_t = R^T (p - t)
    px[m] = R00*ax + R10*ay + R20*az;
    py[m] = R01*ax + R11*ay + R21*az;
    pz[m] = R02*ax + R12*ay + R22*az;
  }
  __syncthreads();

  float best[MI];
  int bg[MI];
  #pragma unroll
  for (int m = 0; m < MI; m++) { best[m] = 3.4e38f; bg[m] = 0; }

  #pragma unroll 2
  for (int g = 0; g < NGROUP; g++) {
    float4 tq[8];
    #pragma unroll
    for (int k = 0; k < 8; k++) tq[k] = tile[8*g + k];
    #pragma unroll
    for (int m = 0; m < MI; m++) {
      float s[8];
      #pragma unroll
      for (int k = 0; k < 8; k++) {
        // score = |t|^2 - 2 p.t  (row-constant |p|^2 omitted; argmin unchanged)
        float v = fmaf(px[m], tq[k].x, tq[k].w);
        v = fmaf(py[m], tq[k].y, v);
        s[k] = fmaf(pz[m], tq[k].z, v);
      }
      float a = fminf(fminf(s[0], s[1]), s[2]);
      float b = fminf(fminf(s[3], s[4]), s[5]);
      float c = fminf(fminf(s[6], s[7]), a);
      float gm = fminf(b, c);
      if (gm < best[m]) { best[m] = gm; bg[m] = g; }
    }
  }

  // rescan winning group for the exact smallest index, then merge globally
  #pragma unroll
  for (int m = 0; m < MI; m++) {
    int jb = 8 * bg[m];
    int bj = 0;
    #pragma unroll
    for (int k = 7; k >= 0; k--) {
      float4 tq = tile[jb + k];
      float v = fmaf(px[m], tq.x, tq.w);
      v = fmaf(py[m], tq.y, v);
      v = fmaf(pz[m], tq.z, v);
      if (v == best[m]) bj = k;     // descending loop -> smallest k wins
    }
    int i = i0 + 256*m;
    unsigned ub = __float_as_uint(best[m]);
    ub = (ub & 0x80000000u) ? ~ub : (ub | 0x80000000u);   // monotone float->uint
    unsigned long long key = ((unsigned long long)ub << 32) |
                             (unsigned long long)(unsigned)(jbase + jb + bj);
    atomicMin(&keys[i], key);
  }
}

// ---------------- accum part: 64 blocks, each reduces 256 points ----------------
__global__ __launch_bounds__(256) void accum_part_kernel(const float* __restrict__ ref,
                                                         const float* __restrict__ trg,
                                                         const float* __restrict__ nrm,
                                                         unsigned long long* __restrict__ keys,
                                                         const State* __restrict__ st,
                                                         float* __restrict__ partials) {
  const int tid = threadIdx.x;
  const int i = blockIdx.x * 256 + tid;

  const float R00 = st->Rc[0], R01 = st->Rc[1], R02 = st->Rc[2];
  const float R10 = st->Rc[3], R11 = st->Rc[4], R12 = st->Rc[5];
  const float R20 = st->Rc[6], R21 = st->Rc[7], R22 = st->Rc[8];
  const float t0 = st->tc[0], t1 = st->tc[1], t2 = st->tc[2];

  unsigned long long key = keys[i];
  keys[i] = 0xFFFFFFFFFFFFFFFFULL;   // reset for next eval
  int j = (int)(unsigned)(key & 0xFFFFFFFFULL);

  float nx0 = nrm[3*j], ny0 = nrm[3*j+1], nz0 = nrm[3*j+2];
  float qx = trg[3*j], qy = trg[3*j+1], qz = trg[3*j+2];
  // n = R * normal ; p = R * trg + t
  float nx = R00*nx0 + R01*ny0 + R02*nz0;
  float ny = R10*nx0 + R11*ny0 + R12*nz0;
  float nz = R20*nx0 + R21*ny0 + R22*nz0;
  float pxx = R00*qx + R01*qy + R02*qz + t0;
  float pyy = R10*qx + R11*qy + R12*qz + t1;
  float pzz = R20*qx + R21*qy + R22*qz + t2;

  float rx = ref[3*i], ry = ref[3*i+1], rz = ref[3*i+2];
  float dxx = rx - pxx, dyy = ry - pyy, dzz = rz - pzz;
  float r = nx*dxx + ny*dyy + nz*dzz;

  float J[6];
  J[0] = ry*nz - rz*ny;
  J[1] = rz*nx - rx*nz;
  J[2] = rx*ny - ry*nx;
  J[3] = nx; J[4] = ny; J[5] = nz;

  float acc[28];
  int c21 = 0;
  #pragma unroll
  for (int a = 0; a < 6; a++)
    #pragma unroll
    for (int b = a; b < 6; b++)
      acc[c21++] = J[a] * J[b];
  #pragma unroll
  for (int a = 0; a < 6; a++) acc[21+a] = J[a] * r;
  acc[27] = r * r;

  // wave shuffle reduce, then cross-wave via LDS
  #pragma unroll
  for (int kk = 0; kk < 28; kk++) {
    float v = acc[kk];
    for (int off = 32; off; off >>= 1) v += __shfl_down(v, off);
    acc[kk] = v;
  }
  __shared__ float red[4][28];
  int wave = tid >> 6, lane = tid & 63;
  if (lane == 0) {
    #pragma unroll
    for (int kk = 0; kk < 28; kk++) red[wave][kk] = acc[kk];
  }
  __syncthreads();
  if (tid < 28) {
    // partials layout: [component][block] so lm_kernel reads contiguously
    partials[tid * 64 + blockIdx.x] =
        red[0][tid] + red[1][tid] + red[2][tid] + red[3][tid];
  }
}

// ---------------- LM scalar update (1 block, 64 threads) ----------------
__global__ __launch_bounds__(64) void lm_kernel(const float* __restrict__ partials,
                                                State* st, float* out, int mode) {
  __shared__ float tot[28];
  const int tid = threadIdx.x;
  if (tid < 28) {
    float s = 0.f;
    #pragma unroll
    for (int b = 0; b < 64; b++) s += partials[tid * 64 + b];
    tot[tid] = s;
  }
  __syncthreads();

  if (tid == 0) {
    float Fn = tot[27];
    float mu, nu;

    if (mode == 0) {
      #pragma unroll
      for (int k = 0; k < 6; k++) st->x[k] = st->xc[k];
      #pragma unroll
      for (int k = 0; k < 21; k++) st->H[k] = tot[k];
      #pragma unroll
      for (int k = 0; k < 6; k++) st->g[k] = tot[21+k];
      st->F = Fn;
      float md = tot[0];
      md = fmaxf(md, tot[6]); md = fmaxf(md, tot[11]); md = fmaxf(md, tot[15]);
      md = fmaxf(md, tot[18]); md = fmaxf(md, tot[20]);
      mu = TAU_C * md;
      nu = 2.f;
    } else {
      mu = st->mu; nu = st->nu;
      float denom = 0.f;
      #pragma unroll
      for (int k = 0; k < 6; k++) denom += st->dx[k] * (mu * st->dx[k] - st->g[k]);
      if (fabsf(denom) < 1e-12f) denom = 1e-12f;
      float rho = (st->F - Fn) / denom;
      if (rho > 0.f) {
        #pragma unroll
        for (int k = 0; k < 6; k++) st->x[k] = st->xc[k];
        #pragma unroll
        for (int k = 0; k < 21; k++) st->H[k] = tot[k];
        #pragma unroll
        for (int k = 0; k < 6; k++) st->g[k] = tot[21+k];
        st->F = Fn;
        float tcube = 2.f * rho - 1.f;
        mu = mu * fmaxf(1.f / 3.f, 1.f - tcube * tcube * tcube);
        nu = 2.f;
      } else {
        mu = mu * nu;
        nu = 2.f * nu;
      }
    }
    st->mu = mu; st->nu = nu;

    if (mode < N_ITER) {
      // solve (H + mu I) d = -g ; SPD -> unpivoted Gauss, fully unrolled
      float A[6][7];
      int c21 = 0;
      #pragma unroll
      for (int a = 0; a < 6; a++)
        #pragma unroll
        for (int b = a; b < 6; b++) { A[a][b] = st->H[c21]; A[b][a] = st->H[c21]; c21++; }
      #pragma unroll
      for (int a = 0; a < 6; a++) { A[a][a] += mu; A[a][6] = -st->g[a]; }
      #pragma unroll
      for (int col = 0; col < 6; col++) {
        float inv = 1.f / A[col][col];
        #pragma unroll
        for (int rI = 0; rI < 6; rI++) {
          if (rI > col) {
            float f = A[rI][col] * inv;
            #pragma unroll
            for (int cc = 0; cc < 7; cc++)
              if (cc >= col) A[rI][cc] -= f * A[col][cc];
          }
        }
      }
      float d[6];
      #pragma unroll
      for (int rI = 5; rI >= 0; rI--) {
        float s = A[rI][6];
        #pragma unroll
        for (int cc = 0; cc < 6; cc++)
          if (cc > rI) s -= A[rI][cc] * d[cc];
        d[rI] = s / A[rI][rI];
      }
      float Rn[9], tn[3];
      #pragma unroll
      for (int k = 0; k < 6; k++) { st->dx[k] = d[k]; st->xc[k] = st->x[k] + d[k]; }
      se3_exp_rt(st->xc, Rn, tn);
      #pragma unroll
      for (int k = 0; k < 9; k++) st->Rc[k] = Rn[k];
      #pragma unroll
      for (int k = 0; k < 3; k++) st->tc[k] = tn[k];
    } else {
      float Rn[9], tn[3];
      se3_exp_rt(st->x, Rn, tn);
      out[0] = Rn[0]; out[1] = Rn[1]; out[2]  = Rn[2]; out[3]  = tn[0];
      out[4] = Rn[3]; out[5] = Rn[4]; out[6]  = Rn[5]; out[7]  = tn[1];
      out[8] = Rn[6]; out[9] = Rn[7]; out[10] = Rn[8]; out[11] = tn[2];
      out[12] = 0.f; out[13] = 0.f; out[14] = 0.f; out[15] = 1.f;
      out[16] = st->F / (float)N_PTS;
    }
  }
}

extern "C" void kernel_launch(void* const* d_in, const int* in_sizes, int n_in,
                              void* d_out, int out_size, void* d_ws, size_t ws_size,
                              hipStream_t stream) {
  const float* ref = (const float*)d_in[0];
  const float* trg = (const float*)d_in[1];
  const float* nrm = (const float*)d_in[2];
  float* out = (float*)d_out;

  char* ws = (char*)d_ws;
  float4* packed = (float4*)ws;                                        // 256 KB
  unsigned long long* keys = (unsigned long long*)(ws + 262144);       // 128 KB
  float* partials = (float*)(ws + 262144 + 131072);                    // 7 KB
  State* st = (State*)(ws + 262144 + 131072 + 8192);

  prep_kernel<<<64, 256, 0, stream>>>(trg, packed, keys, st);
  for (int e = 0; e <= N_ITER; e++) {
    nn_kernel<<<dim3(N_PTS / (256 * MI), N_PTS / BJ), 256, 0, stream>>>(ref, packed, st, keys);
    accum_part_kernel<<<64, 256, 0, stream>>>(ref, trg, nrm, keys, st, partials);
    lm_kernel<<<1, 64, 0, stream>>>(partials, st, out, e);
  }
}